// Round 11
// baseline (280.044 us; speedup 1.0000x reference)
//
#include <hip/hip_runtime.h>
#include <cstdint>
#include <cstddef>

// ---------------------------------------------------------------------------
// Adaptive log-softmax NLL. bf16 MFMA GEMMs fused with online logsumexp.
// R11: transpose was DRAM-READ-segment-bound (256B/k-row at 80KB stride ->
// 2.3 TB/s). New k_transpose3: block = [KB][256n], waves read 1KB contiguous
// per k-row, bf16 LDS tile [64][260], contiguous 16-32KB output spans
// (blocked BT for head/t1, row-major for t2/t3). All GEMMs = R10 (277us best).
// ---------------------------------------------------------------------------

typedef unsigned short u16;
typedef __attribute__((ext_vector_type(8))) __bf16 bf16x8;
typedef __attribute__((ext_vector_type(8))) u16 u16x8;
typedef __attribute__((ext_vector_type(4))) float f32x4;

#define AS1 __attribute__((address_space(1)))
#define AS3 __attribute__((address_space(3)))

__device__ __forceinline__ u16 f2bf(float f){
  union { float f; unsigned u; } v; v.f = f;
  unsigned r = v.u + 0x7fffu + ((v.u >> 16) & 1u);  // RNE
  return (u16)(r >> 16);
}
__device__ __forceinline__ void glds16(const void* g, void* l){
  __builtin_amdgcn_global_load_lds((AS1 unsigned*)(uintptr_t)g,
                                   (AS3 unsigned*)(unsigned)(uintptr_t)l, 16, 0, 0);
}

// ---------------- hidden f32 -> bf16 (+ init cnt and tgt_rel) ----------------
__global__ void k_cvt_hidden(const float* __restrict__ h, u16* __restrict__ a0,
                             int* __restrict__ cnt, int* __restrict__ trel){
  int g = blockIdx.x * 256 + threadIdx.x;
  if (g < 4096) trel[g] = -1;          // tr0..tr3, 1024 each, contiguous
  if (g < 4) cnt[g] = 0;
  int i = g * 8;
  f32x4 v0 = *(const f32x4*)(h + i);
  f32x4 v1 = *(const f32x4*)(h + i + 4);
  u16x8 o;
  o[0]=f2bf(v0.x); o[1]=f2bf(v0.y); o[2]=f2bf(v0.z); o[3]=f2bf(v0.w);
  o[4]=f2bf(v1.x); o[5]=f2bf(v1.y); o[6]=f2bf(v1.z); o[7]=f2bf(v1.w);
  *(u16x8*)(a0 + i) = o;
}

// ---------------- bucket compaction ----------------
// Order within a bucket is atomic-nondeterministic; harmless: per-row values
// are position-independent and results scatter back via pos[n]/idx[p].
__global__ void k_compact(const int* __restrict__ tgt, int* __restrict__ cnt,
                          int* __restrict__ idx1, int* __restrict__ idx2,
                          int* __restrict__ idx3, int* __restrict__ pos,
                          int* __restrict__ tr0, int* __restrict__ tr1,
                          int* __restrict__ tr2, int* __restrict__ tr3){
  int n = blockIdx.x * 256 + threadIdx.x;
  int t = tgt[n];
  int p = 0;
  tr0[n] = (t < 20000) ? t : -1;
  if (t >= 20000){
    int b = (t < 60000) ? 0 : (t < 180000 ? 1 : 2);
    p = atomicAdd(&cnt[b], 1);
    if (b == 0){ idx1[p] = n; tr1[p] = t - 20000; }
    else if (b == 1){ idx2[p] = n; tr2[p] = t - 60000; }
    else { idx3[p] = n; tr3[p] = t - 180000; }
  }
  pos[n] = p;
}

// ---------------- gather compacted tail-A rows ----------------
__global__ void k_gather(const int* __restrict__ cnt,
                         const int* __restrict__ idx1, const int* __restrict__ idx2,
                         const int* __restrict__ idx3,
                         const u16* __restrict__ A1, const u16* __restrict__ A2,
                         const u16* __restrict__ A3,
                         u16* __restrict__ A1c, u16* __restrict__ A2c,
                         u16* __restrict__ A3c){
  int u = blockIdx.x * 256 + threadIdx.x;
  const u16* src; u16* dst;
  if (u < 32768){                       // A1: 1024 rows x 32 chunks(8 elem)
    int r = u >> 5, c = u & 31;
    if (r >= cnt[0]) return;
    src = A1 + (size_t)idx1[r] * 256 + c * 8;
    dst = A1c + (size_t)r * 256 + c * 8;
  } else if (u < 40960){                // A2: 1024 x 8
    int v = u - 32768; int r = v >> 3, c = v & 7;
    if (r >= cnt[1]) return;
    src = A2 + (size_t)idx2[r] * 64 + c * 8;
    dst = A2c + (size_t)r * 64 + c * 8;
  } else {                              // A3 (32-wide): 1024 x 4
    int v = u - 40960; int r = v >> 2, c = v & 3;
    if (r >= cnt[2]) return;
    src = A3 + (size_t)idx3[r] * 32 + c * 8;
    dst = A3c + (size_t)r * 32 + c * 8;
  }
  *(u16x8*)dst = *(const u16x8*)src;
}

// ---------------- multi-job W [K][N] f32 -> BT bf16 (R11 wide-read) --------
// Block = [KB k][256 n], KB = 64 (Kpad>=64) or 32. Stage: wave reads 1KB
// contiguous per k-row; bf16 LDS [64][260] (pad 4: 8B-aligned writes, <=4-way
// read conflicts). Writeout: 16B chunks, contiguous spans in BT (blocked or
// row-major).
struct TJob { const float* W; u16* BT; int K, N, Kpad, nrows, nx, base, blk; };
struct TJobs { TJob j[8]; int nj; };

__global__ void k_transpose3(TJobs jobs){
  __shared__ u16 ls[64 * 260];
  int id = blockIdx.x;
  int ji = 0;
  #pragma unroll
  for (int i = 1; i < 8; ++i)
    if (i < jobs.nj && id >= jobs.j[i].base) ji = i;
  TJob jb = jobs.j[ji];
  int local = id - jb.base;
  const int bx = local % jb.nx;
  const int by = local / jb.nx;
  const int KB = (jb.Kpad >= 64) ? 64 : 32;
  const int n0 = bx * 256, k0 = by * 64;
  const int tid = threadIdx.x, lane = tid & 63, w = tid >> 6;
  const bool al = (jb.N & 3) == 0;

  // ---- stage: KB/4 iterations, 4 k-rows each (1KB contiguous per wave) ----
  for (int it = 0; it < KB / 4; ++it){
    int r = it * 4 + w;
    int k = k0 + r;
    int n = n0 + lane * 4;
    f32x4 v; v.x=0.f; v.y=0.f; v.z=0.f; v.w=0.f;
    if (k < jb.K){
      if (al && n + 3 < jb.N) v = *(const f32x4*)(jb.W + (size_t)k * jb.N + n);
      else { for (int q = 0; q < 4; ++q) if (n + q < jb.N) v[q] = jb.W[(size_t)k * jb.N + n + q]; }
    }
    u16* d = &ls[r * 260 + lane * 4];
    d[0] = f2bf(v.x); d[1] = f2bf(v.y); d[2] = f2bf(v.z); d[3] = f2bf(v.w);
  }
  __syncthreads();

  // ---- writeout: KB/8 iterations x 256 threads x 16B chunks ----
  const int kl3 = (KB == 64) ? 3 : 2;       // log2(chunks per n-row)
  for (int it = 0; it < KB / 8; ++it){
    int c = it * 256 + tid;
    int n = c >> kl3;
    int k8 = (c & ((1 << kl3) - 1)) * 8;
    int gn = n0 + n;
    if (gn < jb.nrows){
      u16x8 o;
      #pragma unroll
      for (int q = 0; q < 8; ++q) o[q] = ls[(k8 + q) * 260 + n];
      size_t off;
      if (jb.blk)
        off = (((size_t)(gn >> 7) * (jb.Kpad >> 6) + (k0 >> 6)) * 128 + (gn & 127)) * 64 + k8;
      else
        off = (size_t)gn * jb.Kpad + k0 + k8;
      *(u16x8*)(jb.BT + off) = o;
    }
  }
}

// ---------------- projection GEMM: A0[1024][1024] x BTp[400][1024]^T -------
// BTp row-major (tiny). cols 0-255 -> A1; 256-319 -> A2; 320-335 -> A3
// (32-wide, col+16 zeroed); 336-338 -> cl (f32, +b_cluster).
__global__ __launch_bounds__(512)
void k_proj_gemm(const u16* __restrict__ A, const u16* __restrict__ BT,
                 const float* __restrict__ bc,
                 u16* __restrict__ A1, u16* __restrict__ A2,
                 u16* __restrict__ A3, float* __restrict__ cl)
{
  constexpr int BK = 64, K = 1024;
  __shared__ u16 As[256 * BK];
  __shared__ u16 Bs[128 * BK];
  const int tid  = threadIdx.x;
  const int lane = tid & 63, wid = tid >> 6;
  const int wm = wid & 3, wn = wid >> 2;
  const int l15 = lane & 15, l4 = lane >> 4;
  const int m0 = blockIdx.y * 256;
  const int n0 = blockIdx.x * 128;

  f32x4 acc[4][4];
  #pragma unroll
  for (int m = 0; m < 4; ++m)
    #pragma unroll
    for (int n = 0; n < 4; ++n){ acc[m][n].x=0.f; acc[m][n].y=0.f; acc[m][n].z=0.f; acc[m][n].w=0.f; }

  for (int kt = 0; kt < K / BK; ++kt){
    #pragma unroll
    for (int i = 0; i < 4; ++i){
      int c = wid * 4 + i;
      int row = c * 8 + lane / 8, kb = lane % 8;
      glds16((const char*)(A + (size_t)(m0 + row) * K + kt * BK) + kb * 16,
             (char*)As + c * 1024);
    }
    #pragma unroll
    for (int i = 0; i < 2; ++i){
      int c = wid * 2 + i;
      int row = c * 8 + lane / 8, kb = lane % 8;
      glds16((const char*)(BT + (size_t)(n0 + row) * K + kt * BK) + kb * 16,
             (char*)Bs + c * 1024);
    }
    __syncthreads();
    #pragma unroll
    for (int ks = 0; ks < 2; ++ks){
      bf16x8 af[4], bfr[4];
      #pragma unroll
      for (int m = 0; m < 4; ++m)
        af[m] = *(const bf16x8*)((const char*)As + (wm*64 + m*16 + l15) * (BK*2) + ks*64 + l4*16);
      #pragma unroll
      for (int n = 0; n < 4; ++n)
        bfr[n] = *(const bf16x8*)((const char*)Bs + (wn*64 + n*16 + l15) * (BK*2) + ks*64 + l4*16);
      #pragma unroll
      for (int m = 0; m < 4; ++m)
        #pragma unroll
        for (int n = 0; n < 4; ++n)
          acc[m][n] = __builtin_amdgcn_mfma_f32_16x16x32_bf16(af[m], bfr[n], acc[m][n], 0, 0, 0);
    }
    __syncthreads();
  }
  #pragma unroll
  for (int m = 0; m < 4; ++m)
    #pragma unroll
    for (int n = 0; n < 4; ++n)
      #pragma unroll
      for (int q = 0; q < 4; ++q){
        int c = n0 + wn*64 + n*16 + l15;
        int r = m0 + wm*64 + m*16 + l4*4 + q;
        float v = acc[m][n][q];
        if (c < 256)      A1[(size_t)r*256 + c] = f2bf(v);
        else if (c < 320) A2[(size_t)r*64 + (c-256)] = f2bf(v);
        else if (c < 336){ u16* p = A3 + (size_t)r*32 + (c-320);
                           p[0] = f2bf(v); p[16] = 0; }
        else if (c < 339) cl[(size_t)r*3 + (c-336)] = v + bc[c-336];
      }
}

// ---------------- standard GEMM + direct-sum LSE (head, t1) ----------------
// 128x128, BK=64, 4 waves, 2-barrier loop, T2 swizzle. P = f32 sum of exp.
// BLK: B is in K-blocked layout [cb][kt][128][64].
template<int BK, bool BLK>
__global__ __launch_bounds__(256)
void k_gemm_lse(const u16* __restrict__ A, const u16* __restrict__ BT,
                const float* __restrict__ bias, int K, int N,
                float* __restrict__ P, int ntiles,
                const int* __restrict__ cntp, int bucket,
                const int* __restrict__ tgt_rel, const int* __restrict__ rowmap,
                float* __restrict__ tl)
{
  if (cntp && (int)(blockIdx.y * 128) >= cntp[bucket]) return;
  __shared__ u16 As[128 * BK];
  __shared__ u16 Bs[128 * BK];
  __shared__ float reds[2][128];
  __shared__ int trel_s[128];

  const int tid  = threadIdx.x;
  const int lane = tid & 63, wid = tid >> 6;
  const int wm = wid & 1, wn = wid >> 1;
  const int l15 = lane & 15, l4 = lane >> 4;
  const int m0 = blockIdx.y * 128;
  const int n0 = blockIdx.x * 128;
  const int srow = lane >> 3, skb = lane & 7;

  if (tid < 128) trel_s[tid] = tgt_rel[m0 + tid];

  f32x4 acc[4][4];
  #pragma unroll
  for (int m = 0; m < 4; ++m)
    #pragma unroll
    for (int n = 0; n < 4; ++n){ acc[m][n].x=0.f; acc[m][n].y=0.f; acc[m][n].z=0.f; acc[m][n].w=0.f; }

  const int ksteps = K / BK;
  for (int kt = 0; kt < ksteps; ++kt){
    #pragma unroll
    for (int i = 0; i < 4; ++i){
      int c = wid * 4 + i;
      int row = c * 8 + srow;
      int kbs = skb ^ (row & 7);
      glds16((const char*)(A + (size_t)(m0 + row) * K + kt * BK) + kbs * 16,
             (char*)As + c * 1024);
    }
    #pragma unroll
    for (int i = 0; i < 4; ++i){
      int c = wid * 4 + i;
      int row = c * 8 + srow;
      int kbs = skb ^ (row & 7);
      const char* src;
      if (BLK)
        src = (const char*)(BT + ((size_t)(blockIdx.x * ksteps + kt) * 128 + row) * 64);
      else
        src = (const char*)(BT + (size_t)(n0 + row) * K + kt * BK);
      glds16(src + kbs * 16, (char*)Bs + c * 1024);
    }
    __syncthreads();
    #pragma unroll
    for (int ks = 0; ks < 2; ++ks){
      bf16x8 af[4], bfr[4];
      #pragma unroll
      for (int m = 0; m < 4; ++m){
        int r = wm*64 + m*16 + l15;
        af[m] = *(const bf16x8*)((const char*)As + r*(BK*2) + (((ks*4 + l4) ^ (r & 7)) * 16));
      }
      #pragma unroll
      for (int n = 0; n < 4; ++n){
        int r = wn*64 + n*16 + l15;
        bfr[n] = *(const bf16x8*)((const char*)Bs + r*(BK*2) + (((ks*4 + l4) ^ (r & 7)) * 16));
      }
      #pragma unroll
      for (int m = 0; m < 4; ++m)
        #pragma unroll
        for (int n = 0; n < 4; ++n)
          acc[m][n] = __builtin_amdgcn_mfma_f32_16x16x32_bf16(af[m], bfr[n], acc[m][n], 0, 0, 0);
    }
    __syncthreads();
  }

  // ---- epilogue: direct sum of exp over this 128-col tile ----
  float bv[4]; bool val[4];
  #pragma unroll
  for (int n = 0; n < 4; ++n){
    int col = n0 + wn*64 + n*16 + l15;
    val[n] = col < N;
    bv[n] = val[n] ? bias[col] : 0.f;
  }
  #pragma unroll
  for (int m = 0; m < 4; ++m)
    #pragma unroll
    for (int q = 0; q < 4; ++q){
      int lrow = wm*64 + m*16 + l4*4 + q;
      int tr = trel_s[lrow];
      float Sl = 0.f;
      #pragma unroll
      for (int n = 0; n < 4; ++n){
        if (val[n]){
          float lg = acc[m][n][q] + bv[n];
          Sl += __expf(lg);
          int col = n0 + wn*64 + n*16 + l15;
          if (tr == col) tl[rowmap ? rowmap[m0 + lrow] : (m0 + lrow)] = lg;
        }
      }
      #pragma unroll
      for (int d = 1; d < 16; d <<= 1) Sl += __shfl_xor(Sl, d);
      if (l15 == 0) reds[wn][lrow] = Sl;
    }
  __syncthreads();
  if (wn == 0 && l15 == 0){
    #pragma unroll
    for (int m = 0; m < 4; ++m)
      #pragma unroll
      for (int q = 0; q < 4; ++q){
        int lrow = wm*64 + m*16 + l4*4 + q;
        P[(size_t)(m0 + lrow) * ntiles + blockIdx.x] = reds[0][lrow] + reds[1][lrow];
      }
  }
}

// ---------------- B-streaming GEMM for 1-K-step tails (t2 BK=64, t3 BK=32) --
template<int NC, int BK>
__global__ __launch_bounds__(256)
void k_gemm_lse_s(const u16* __restrict__ A, const u16* __restrict__ BT,
                  const float* __restrict__ bias, int N,
                  float* __restrict__ P, int ntiles,
                  const int* __restrict__ cntp, int bucket,
                  const int* __restrict__ tgt_rel, const int* __restrict__ rowmap,
                  float* __restrict__ tl)
{
  constexpr int CH  = BK / 8;          // 16B chunks per row
  constexpr int LPR = CH;
  constexpr int RPC = 64 / LPR;
  constexpr int CPW = (128 * BK * 2 / 1024) / 4;  // 1KB chunks per wave
  const int m0 = blockIdx.y * 128;
  if (m0 >= cntp[bucket]) return;
  const int cg = blockIdx.x;

  __shared__ u16 As[128 * BK];
  __shared__ u16 Bs[2][128 * BK];
  __shared__ float reds[2][128];
  __shared__ int trel_s[128];

  const int tid  = threadIdx.x;
  const int lane = tid & 63, wid = tid >> 6;
  const int wm = wid & 1, wn = wid >> 1;
  const int l15 = lane & 15, l4 = lane >> 4;
  const int srow = lane / LPR, skb = lane % LPR;

  if (tid < 128) trel_s[tid] = tgt_rel[m0 + tid];

  #pragma unroll
  for (int i = 0; i < CPW; ++i){
    int c = wid * CPW + i;
    int row = c * RPC + srow;
    int kbs = skb ^ (row & (CH - 1));
    glds16((const char*)(A + (size_t)(m0 + row) * BK) + kbs * 16,
           (char*)As + c * 1024);
  }
  {
    int ci0 = cg * NC;
    if (ci0 < ntiles){
      #pragma unroll
      for (int i = 0; i < CPW; ++i){
        int c = wid * CPW + i;
        int row = c * RPC + srow;
        int kbs = skb ^ (row & (CH - 1));
        glds16((const char*)(BT + (size_t)(ci0*128 + row) * BK) + kbs * 16,
               (char*)Bs[0] + c * 1024);
      }
    }
  }
  __syncthreads();

  int buf = 0;
  for (int ct = 0; ct < NC; ++ct){
    int ci = cg * NC + ct;
    if (ci >= ntiles) break;
    if (ct + 1 < NC && ci + 1 < ntiles){
      #pragma unroll
      for (int i = 0; i < CPW; ++i){
        int c = wid * CPW + i;
        int row = c * RPC + srow;
        int kbs = skb ^ (row & (CH - 1));
        glds16((const char*)(BT + (size_t)((ci+1)*128 + row) * BK) + kbs * 16,
               (char*)Bs[buf ^ 1] + c * 1024);
      }
    }
    f32x4 acc[4][4];
    #pragma unroll
    for (int m = 0; m < 4; ++m)
      #pragma unroll
      for (int n = 0; n < 4; ++n){ acc[m][n].x=0.f; acc[m][n].y=0.f; acc[m][n].z=0.f; acc[m][n].w=0.f; }
    #pragma unroll
    for (int ks = 0; ks < BK / 32; ++ks){
      bf16x8 af[4], bfr[4];
      #pragma unroll
      for (int m = 0; m < 4; ++m){
        int r = wm*64 + m*16 + l15;
        af[m] = *(const bf16x8*)((const char*)As + r*(BK*2) + (((ks*4 + l4) ^ (r & (CH-1))) * 16));
      }
      #pragma unroll
      for (int n = 0; n < 4; ++n){
        int r = wn*64 + n*16 + l15;
        bfr[n] = *(const bf16x8*)((const char*)Bs[buf] + r*(BK*2) + (((ks*4 + l4) ^ (r & (CH-1))) * 16));
      }
      #pragma unroll
      for (int m = 0; m < 4; ++m)
        #pragma unroll
        for (int n = 0; n < 4; ++n)
          acc[m][n] = __builtin_amdgcn_mfma_f32_16x16x32_bf16(af[m], bfr[n], acc[m][n], 0, 0, 0);
    }
    const int n0 = ci * 128;
    float bv[4]; bool val[4];
    #pragma unroll
    for (int n = 0; n < 4; ++n){
      int col = n0 + wn*64 + n*16 + l15;
      val[n] = col < N;
      bv[n] = val[n] ? bias[col] : 0.f;
    }
    #pragma unroll
    for (int m = 0; m < 4; ++m)
      #pragma unroll
      for (int q = 0; q < 4; ++q){
        int lrow = wm*64 + m*16 + l4*4 + q;
        int tr = trel_s[lrow];
        float Sl = 0.f;
        #pragma unroll
        for (int n = 0; n < 4; ++n){
          if (val[n]){
            float lg = acc[m][n][q] + bv[n];
            Sl += __expf(lg);
            int col = n0 + wn*64 + n*16 + l15;
            if (tr == col) tl[rowmap[m0 + lrow]] = lg;
          }
        }
        #pragma unroll
        for (int d = 1; d < 16; d <<= 1) Sl += __shfl_xor(Sl, d);
        if (l15 == 0) reds[wn][lrow] = Sl;
      }
    __syncthreads();
    if (wn == 0 && l15 == 0){
      #pragma unroll
      for (int m = 0; m < 4; ++m)
        #pragma unroll
        for (int q = 0; q < 4; ++q){
          int lrow = wm*64 + m*16 + l4*4 + q;
          P[(size_t)(m0 + lrow) * ntiles + ci] = reds[0][lrow] + reds[1][lrow];
        }
    }
    __syncthreads();
    buf ^= 1;
  }
}

// ---------------- final combine (P = f32 partial sums of exp) ----------------
__global__ void k_finalize(const int* __restrict__ tgt, const float* __restrict__ P,
                           const float* __restrict__ cl, const float* __restrict__ tl,
                           const int* __restrict__ pos, float* __restrict__ out)
{
  const int NT0 = 157, NT1 = 313, NT2 = 938, NT3 = 686;
  int n = blockIdx.x * 4 + (threadIdx.x >> 6);
  int lane = threadIdx.x & 63;
  int t = tgt[n];

  float s = 0.f;
  const float* p0 = P + (size_t)n * NT0;
  for (int i = lane; i < NT0; i += 64) s += p0[i];
  if (lane < 3) s += __expf(cl[n*3 + lane]);
  #pragma unroll
  for (int d = 1; d < 64; d <<= 1) s += __shfl_xor(s, d);
  float lse_head = logf(s);

  float nll;
  if (t < 20000){
    nll = lse_head - tl[n];
  } else {
    int seg, nt; size_t base;
    if      (t <  60000){ seg = 1; nt = NT1; base = (size_t)1024 * NT0; }
    else if (t < 180000){ seg = 2; nt = NT2; base = (size_t)1024 * (NT0 + NT1); }
    else                { seg = 3; nt = NT3; base = (size_t)1024 * (NT0 + NT1 + NT2); }
    float s2 = 0.f;
    const float* ps = P + base + (size_t)pos[n] * nt;
    for (int i = lane; i < nt; i += 64) s2 += ps[i];
    #pragma unroll
    for (int d = 1; d < 64; d <<= 1) s2 += __shfl_xor(s2, d);
    float lse_t = logf(s2);
    // reference quirk: bucket i uses head_lp[:, -i] == cluster logit index 3-i
    nll = lse_head - cl[n*3 + (3 - seg)] + lse_t - tl[n];
  }
  if (lane == 0) out[n] = nll;
}

// ---------------------------------------------------------------------------
extern "C" void kernel_launch(void* const* d_in, const int* in_sizes, int n_in,
                              void* d_out, int out_size, void* d_ws, size_t ws_size,
                              hipStream_t stream)
{
  const float* hidden = (const float*)d_in[0];
  const int*   target = (const int*)d_in[1];
  const float* W_head = (const float*)d_in[2];
  const float* b_head = (const float*)d_in[3];
  const float* W_clu  = (const float*)d_in[4];
  const float* b_clu  = (const float*)d_in[5];
  const float* W_p1   = (const float*)d_in[6];
  const float* W_t1   = (const float*)d_in[7];
  const float* b_t1   = (const float*)d_in[8];
  const float* W_p2   = (const float*)d_in[9];
  const float* W_t2   = (const float*)d_in[10];
  const float* b_t2   = (const float*)d_in[11];
  const float* W_p3   = (const float*)d_in[12];
  const float* W_t3   = (const float*)d_in[13];
  const float* b_t3   = (const float*)d_in[14];
  float* out = (float*)d_out;

  // workspace layout (bytes; big path needs ~100 MB)
  char* ws = (char*)d_ws;
  u16*   A0  = (u16*)(ws + 0);          // [1024][1024] bf16
  u16*   A1  = (u16*)(ws + 2097152);    // [1024][256]
  u16*   A2  = (u16*)(ws + 2621440);    // [1024][64]
  u16*   A3  = (u16*)(ws + 2752512);    // [1024][32]
  float* cl  = (float*)(ws + 2883584);  // [1024][3]
  float* tl  = (float*)(ws + 2895872);  // [1024]
  float* P   = (float*)(ws + 2899968);  // [1024][157+313+938+686] f32 (8.6MB)
  u16*   BTp = (u16*)(ws + 2899968);    // proj weights [400][1024]; dead
                                        // before head GEMM writes P
  u16*   BTh = (u16*)(ws + 11476992);   // head BT blocked [157][16][128][64]
  int*   cnt  = (int*)(ws + 52633600);  // [4]
  int*   idx1 = (int*)(ws + 52633856);
  int*   idx2 = (int*)(ws + 52637952);
  int*   idx3 = (int*)(ws + 52642048);
  int*   pos  = (int*)(ws + 52646144);
  u16*   A1c  = (u16*)(ws + 52650240);  // [1024][256]
  u16*   A2c  = (u16*)(ws + 53174528);  // [1024][64]
  u16*   A3c  = (u16*)(ws + 53305600);  // [1024][32]
  int*   tr0  = (int*)(ws + 53436672);  // [1024] x4, contiguous
  int*   tr1  = (int*)(ws + 53440768);
  int*   tr2  = (int*)(ws + 53444864);
  int*   tr3  = (int*)(ws + 53448960);
  u16*   BT1  = (u16*)(ws + 53453056);  // t1 blocked [313][4][128][64] (20.5MB)
  u16*   BT2  = (u16*)(ws + 73965824);  // [120064][64]  (15.4 MB)
  u16*   BT3  = (u16*)(ws + 89334016);  // [87808][32]   ( 5.6 MB)
  const size_t needA = 95000000;
  const bool bigws = ws_size >= needA;

  float* P0  = P;
  float* Pp1 = P + (size_t)1024 * 157;
  float* Pp2 = P + (size_t)1024 * (157 + 313);
  float* Pp3 = P + (size_t)1024 * (157 + 313 + 938);

  k_cvt_hidden<<<512, 256, 0, stream>>>(hidden, A0, cnt, tr0);
  k_compact<<<4, 256, 0, stream>>>(target, cnt, idx1, idx2, idx3, pos,
                                   tr0, tr1, tr2, tr3);

  // ---- transposes (R11 geometry: 256-n x KB-k per block) ----
  TJobs tj{}; int nb = 0;
  auto add = [&](const float* W, u16* B, int K, int N, int Kpad, int nrows, int blk){
    int nx = (nrows + 255) / 256;
    int ny = (Kpad >= 64) ? (Kpad / 64) : 1;
    tj.j[tj.nj++] = TJob{W, B, K, N, Kpad, nrows, nx, nb, blk};
    nb += nx * ny;
  };
  add(W_p1, BTp, 1024, 256, 1024, 256, 0);
  add(W_p2, BTp + (size_t)256*1024, 1024, 64, 1024, 64, 0);
  add(W_p3, BTp + (size_t)320*1024, 1024, 16, 1024, 16, 0);
  add(W_clu, BTp + (size_t)336*1024, 1024, 3, 1024, 64, 0);
  add(W_head, BTh, 1024, 20000, 1024, 20096, 1);
  if (bigws){
    add(W_t1, BT1, 256, 40000, 256, 40064, 1);
    add(W_t2, BT2, 64, 120000, 64, 120064, 0);
    add(W_t3, BT3, 16, 87735, 32, 87808, 0);
  }
  k_transpose3<<<nb, 256, 0, stream>>>(tj);

  k_proj_gemm<<<dim3(3, 4), 512, 0, stream>>>(A0, BTp, b_clu, A1, A2, A3, cl);
  k_gather<<<192, 256, 0, stream>>>(cnt, idx1, idx2, idx3, A1, A2, A3, A1c, A2c, A3c);

  // ---- GEMM+LSE per segment (split launches: R3/R7-proven) ----
  k_gemm_lse<64, true><<<dim3(157, 8), 256, 0, stream>>>(A0, BTh, b_head, 1024, 20000,
      P0, 157, nullptr, 0, tr0, nullptr, tl);

  if (bigws){
    k_gemm_lse<64, true><<<dim3(313, 8), 256, 0, stream>>>(A1c, BT1, b_t1, 256, 40000,
        Pp1, 313, cnt, 0, tr1, idx1, tl);
    k_gemm_lse_s<4, 64><<<dim3(235, 8), 256, 0, stream>>>(A2c, BT2, b_t2, 120000,
        Pp2, 938, cnt, 1, tr2, idx2, tl);
    k_gemm_lse_s<4, 32><<<dim3(172, 8), 256, 0, stream>>>(A3c, BT3, b_t3, 87735,
        Pp3, 686, cnt, 2, tr3, idx3, tl);
  } else {
    // small ws: tails sequentially reuse BTh region (each fits in 41 MB)
    TJobs s1{}; s1.nj = 1; s1.j[0] = TJob{W_t1, BTh, 256, 40000, 256, 40064, 157, 0, 1};
    k_transpose3<<<157*4, 256, 0, stream>>>(s1);
    k_gemm_lse<64, true><<<dim3(313, 8), 256, 0, stream>>>(A1c, BTh, b_t1, 256, 40000,
        Pp1, 313, cnt, 0, tr1, idx1, tl);
    TJobs s2{}; s2.nj = 1; s2.j[0] = TJob{W_t2, BTh, 64, 120000, 64, 120064, 469, 0, 0};
    k_transpose3<<<469, 256, 0, stream>>>(s2);
    k_gemm_lse_s<4, 64><<<dim3(235, 8), 256, 0, stream>>>(A2c, BTh, b_t2, 120000,
        Pp2, 938, cnt, 1, tr2, idx2, tl);
    TJobs s3{}; s3.nj = 1; s3.j[0] = TJob{W_t3, BTh, 16, 87735, 32, 87808, 343, 0, 0};
    k_transpose3<<<343, 256, 0, stream>>>(s3);
    k_gemm_lse_s<4, 32><<<dim3(172, 8), 256, 0, stream>>>(A3c, BTh, b_t3, 87735,
        Pp3, 686, cnt, 2, tr3, idx3, tl);
  }

  k_finalize<<<256, 256, 0, stream>>>(target, P, cl, tl, pos, out);
}

// Round 13
// 274.288 us; speedup vs baseline: 1.0210x; 1.0210x over previous
//
#include <hip/hip_runtime.h>
#include <cstdint>
#include <cstddef>

// ---------------------------------------------------------------------------
// Adaptive log-softmax NLL. bf16 MFMA GEMMs fused with online logsumexp.
// R13: R12 with the k_gemm_lse256 staging-count bug fixed (A = 32 chunks =
// 4/wave, B = 16 chunks = 2/wave; R12 staged half -> 0xAA garbage -> NaN).
// head/t1 = BM 256x128 8-wave + blocked-B + direct-sum epilogue; transpose,
// t2/t3 B-streaming, proj, finalize identical to R10 (277.4us best).
// ---------------------------------------------------------------------------

typedef unsigned short u16;
typedef __attribute__((ext_vector_type(8))) __bf16 bf16x8;
typedef __attribute__((ext_vector_type(8))) u16 u16x8;
typedef __attribute__((ext_vector_type(4))) float f32x4;

#define AS1 __attribute__((address_space(1)))
#define AS3 __attribute__((address_space(3)))

__device__ __forceinline__ u16 f2bf(float f){
  union { float f; unsigned u; } v; v.f = f;
  unsigned r = v.u + 0x7fffu + ((v.u >> 16) & 1u);  // RNE
  return (u16)(r >> 16);
}
__device__ __forceinline__ void glds16(const void* g, void* l){
  __builtin_amdgcn_global_load_lds((AS1 unsigned*)(uintptr_t)g,
                                   (AS3 unsigned*)(unsigned)(uintptr_t)l, 16, 0, 0);
}

// ---------------- hidden f32 -> bf16 (+ init cnt and tgt_rel) ----------------
__global__ void k_cvt_hidden(const float* __restrict__ h, u16* __restrict__ a0,
                             int* __restrict__ cnt, int* __restrict__ trel){
  int g = blockIdx.x * 256 + threadIdx.x;
  if (g < 4096) trel[g] = -1;          // tr0..tr3, 1024 each, contiguous
  if (g < 4) cnt[g] = 0;
  int i = g * 8;
  f32x4 v0 = *(const f32x4*)(h + i);
  f32x4 v1 = *(const f32x4*)(h + i + 4);
  u16x8 o;
  o[0]=f2bf(v0.x); o[1]=f2bf(v0.y); o[2]=f2bf(v0.z); o[3]=f2bf(v0.w);
  o[4]=f2bf(v1.x); o[5]=f2bf(v1.y); o[6]=f2bf(v1.z); o[7]=f2bf(v1.w);
  *(u16x8*)(a0 + i) = o;
}

// ---------------- bucket compaction ----------------
// Order within a bucket is atomic-nondeterministic; harmless: per-row values
// are position-independent and results scatter back via pos[n]/idx[p].
__global__ void k_compact(const int* __restrict__ tgt, int* __restrict__ cnt,
                          int* __restrict__ idx1, int* __restrict__ idx2,
                          int* __restrict__ idx3, int* __restrict__ pos,
                          int* __restrict__ tr0, int* __restrict__ tr1,
                          int* __restrict__ tr2, int* __restrict__ tr3){
  int n = blockIdx.x * 256 + threadIdx.x;
  int t = tgt[n];
  int p = 0;
  tr0[n] = (t < 20000) ? t : -1;
  if (t >= 20000){
    int b = (t < 60000) ? 0 : (t < 180000 ? 1 : 2);
    p = atomicAdd(&cnt[b], 1);
    if (b == 0){ idx1[p] = n; tr1[p] = t - 20000; }
    else if (b == 1){ idx2[p] = n; tr2[p] = t - 60000; }
    else { idx3[p] = n; tr3[p] = t - 180000; }
  }
  pos[n] = p;
}

// ---------------- gather compacted tail-A rows ----------------
__global__ void k_gather(const int* __restrict__ cnt,
                         const int* __restrict__ idx1, const int* __restrict__ idx2,
                         const int* __restrict__ idx3,
                         const u16* __restrict__ A1, const u16* __restrict__ A2,
                         const u16* __restrict__ A3,
                         u16* __restrict__ A1c, u16* __restrict__ A2c,
                         u16* __restrict__ A3c){
  int u = blockIdx.x * 256 + threadIdx.x;
  const u16* src; u16* dst;
  if (u < 32768){                       // A1: 1024 rows x 32 chunks(8 elem)
    int r = u >> 5, c = u & 31;
    if (r >= cnt[0]) return;
    src = A1 + (size_t)idx1[r] * 256 + c * 8;
    dst = A1c + (size_t)r * 256 + c * 8;
  } else if (u < 40960){                // A2: 1024 x 8
    int v = u - 32768; int r = v >> 3, c = v & 7;
    if (r >= cnt[1]) return;
    src = A2 + (size_t)idx2[r] * 64 + c * 8;
    dst = A2c + (size_t)r * 64 + c * 8;
  } else {                              // A3 (32-wide): 1024 x 4
    int v = u - 40960; int r = v >> 2, c = v & 3;
    if (r >= cnt[2]) return;
    src = A3 + (size_t)idx3[r] * 32 + c * 8;
    dst = A3c + (size_t)r * 32 + c * 8;
  }
  *(u16x8*)dst = *(const u16x8*)src;
}

// ---------------- multi-job W [K][N] f32 -> BT bf16 (R10 version) ----------
// blocked element offset(n,k) = ((n>>7)*(Kpad>>6) + (k>>6))*8192 + (n&127)*64
//                               + (k&63)  -> 64x64 tile = one 8KB span.
struct TJob { const float* W; u16* BT; int K, N, Kpad, nrows, nx, base, blk; };
struct TJobs { TJob j[8]; int nj; };

__global__ void k_transpose_multi(TJobs jobs){
  int id = blockIdx.x;
  int ji = 0;
  #pragma unroll
  for (int i = 1; i < 8; ++i)
    if (i < jobs.nj && id >= jobs.j[i].base) ji = i;
  TJob jb = jobs.j[ji];
  int local = id - jb.base;
  int bx = local % jb.nx;
  int by = local / jb.nx;

  __shared__ float t[64][65];
  const int n0 = bx * 64;
  const int k0 = by * 64;
  const bool al = (jb.N & 3) == 0;
  for (int i = threadIdx.x; i < 64*16; i += 256){
    int r = i >> 4, c4 = (i & 15) * 4;
    int k = k0 + r, n = n0 + c4;
    f32x4 v; v.x=0.f; v.y=0.f; v.z=0.f; v.w=0.f;
    if (k < jb.K){
      if (al && n + 3 < jb.N) v = *(const f32x4*)(jb.W + (size_t)k * jb.N + n);
      else { for (int q = 0; q < 4; ++q) if (n + q < jb.N) v[q] = jb.W[(size_t)k * jb.N + n + q]; }
    }
    t[r][c4] = v.x; t[r][c4+1] = v.y; t[r][c4+2] = v.z; t[r][c4+3] = v.w;
  }
  __syncthreads();
  for (int i = threadIdx.x; i < 64*8; i += 256){
    int rn = i >> 3, c8 = (i & 7) * 8;
    int n = n0 + rn;
    if (k0 + c8 < jb.Kpad && n < jb.nrows){
      u16x8 o;
      #pragma unroll
      for (int q = 0; q < 8; ++q) o[q] = f2bf(t[c8 + q][rn]);
      size_t off;
      if (jb.blk)
        off = (((size_t)(n >> 7) * (jb.Kpad >> 6) + (k0 >> 6)) * 128 + (n & 127)) * 64 + c8;
      else
        off = (size_t)n * jb.Kpad + k0 + c8;
      *(u16x8*)(jb.BT + off) = o;
    }
  }
}

// ---------------- projection GEMM: A0[1024][1024] x BTp[400][1024]^T -------
// BTp row-major (tiny). cols 0-255 -> A1; 256-319 -> A2; 320-335 -> A3
// (32-wide, col+16 zeroed); 336-338 -> cl (f32, +b_cluster).
__global__ __launch_bounds__(512)
void k_proj_gemm(const u16* __restrict__ A, const u16* __restrict__ BT,
                 const float* __restrict__ bc,
                 u16* __restrict__ A1, u16* __restrict__ A2,
                 u16* __restrict__ A3, float* __restrict__ cl)
{
  constexpr int BK = 64, K = 1024;
  __shared__ u16 As[256 * BK];
  __shared__ u16 Bs[128 * BK];
  const int tid  = threadIdx.x;
  const int lane = tid & 63, wid = tid >> 6;
  const int wm = wid & 3, wn = wid >> 2;
  const int l15 = lane & 15, l4 = lane >> 4;
  const int m0 = blockIdx.y * 256;
  const int n0 = blockIdx.x * 128;

  f32x4 acc[4][4];
  #pragma unroll
  for (int m = 0; m < 4; ++m)
    #pragma unroll
    for (int n = 0; n < 4; ++n){ acc[m][n].x=0.f; acc[m][n].y=0.f; acc[m][n].z=0.f; acc[m][n].w=0.f; }

  for (int kt = 0; kt < K / BK; ++kt){
    #pragma unroll
    for (int i = 0; i < 4; ++i){
      int c = wid * 4 + i;
      int row = c * 8 + lane / 8, kb = lane % 8;
      glds16((const char*)(A + (size_t)(m0 + row) * K + kt * BK) + kb * 16,
             (char*)As + c * 1024);
    }
    #pragma unroll
    for (int i = 0; i < 2; ++i){
      int c = wid * 2 + i;
      int row = c * 8 + lane / 8, kb = lane % 8;
      glds16((const char*)(BT + (size_t)(n0 + row) * K + kt * BK) + kb * 16,
             (char*)Bs + c * 1024);
    }
    __syncthreads();
    #pragma unroll
    for (int ks = 0; ks < 2; ++ks){
      bf16x8 af[4], bfr[4];
      #pragma unroll
      for (int m = 0; m < 4; ++m)
        af[m] = *(const bf16x8*)((const char*)As + (wm*64 + m*16 + l15) * (BK*2) + ks*64 + l4*16);
      #pragma unroll
      for (int n = 0; n < 4; ++n)
        bfr[n] = *(const bf16x8*)((const char*)Bs + (wn*64 + n*16 + l15) * (BK*2) + ks*64 + l4*16);
      #pragma unroll
      for (int m = 0; m < 4; ++m)
        #pragma unroll
        for (int n = 0; n < 4; ++n)
          acc[m][n] = __builtin_amdgcn_mfma_f32_16x16x32_bf16(af[m], bfr[n], acc[m][n], 0, 0, 0);
    }
    __syncthreads();
  }
  #pragma unroll
  for (int m = 0; m < 4; ++m)
    #pragma unroll
    for (int n = 0; n < 4; ++n)
      #pragma unroll
      for (int q = 0; q < 4; ++q){
        int c = n0 + wn*64 + n*16 + l15;
        int r = m0 + wm*64 + m*16 + l4*4 + q;
        float v = acc[m][n][q];
        if (c < 256)      A1[(size_t)r*256 + c] = f2bf(v);
        else if (c < 320) A2[(size_t)r*64 + (c-256)] = f2bf(v);
        else if (c < 336){ u16* p = A3 + (size_t)r*32 + (c-320);
                           p[0] = f2bf(v); p[16] = 0; }
        else if (c < 339) cl[(size_t)r*3 + (c-336)] = v + bc[c-336];
      }
}

// ---------------- BM=256 GEMM + direct-sum LSE (head, t1) ----------------
// 256x128, BK=64, 8 waves (wm=wid&3, wn=wid>>2), 2-barrier loop, T2 swizzle,
// B in K-blocked layout [cb][kt][128][64]. P = f32 sum of exp.
// Staging: A = 32x1KB chunks (4/wave), B = 16 (2/wave)  [R12 bug: was 16/8].
__global__ __launch_bounds__(512)
void k_gemm_lse256(const u16* __restrict__ A, const u16* __restrict__ BT,
                   const float* __restrict__ bias, int K, int N,
                   float* __restrict__ P, int ntiles,
                   const int* __restrict__ cntp, int bucket,
                   const int* __restrict__ tgt_rel, const int* __restrict__ rowmap,
                   float* __restrict__ tl)
{
  constexpr int BK = 64;
  if (cntp && (int)(blockIdx.y * 256) >= cntp[bucket]) return;
  __shared__ u16 As[256 * BK];
  __shared__ u16 Bs[128 * BK];
  __shared__ float reds[2][256];
  __shared__ int trel_s[256];

  const int tid  = threadIdx.x;
  const int lane = tid & 63, wid = tid >> 6;
  const int wm = wid & 3, wn = wid >> 2;
  const int l15 = lane & 15, l4 = lane >> 4;
  const int m0 = blockIdx.y * 256;
  const int n0 = blockIdx.x * 128;
  const int srow = lane >> 3, skb = lane & 7;

  if (tid < 256) trel_s[tid] = tgt_rel[m0 + tid];

  f32x4 acc[4][4];
  #pragma unroll
  for (int m = 0; m < 4; ++m)
    #pragma unroll
    for (int n = 0; n < 4; ++n){ acc[m][n].x=0.f; acc[m][n].y=0.f; acc[m][n].z=0.f; acc[m][n].w=0.f; }

  const int ksteps = K / BK;
  for (int kt = 0; kt < ksteps; ++kt){
    #pragma unroll
    for (int i = 0; i < 4; ++i){                    // A: 32 chunks, 4/wave
      int c = wid * 4 + i;
      int row = c * 8 + srow;
      int kbs = skb ^ (row & 7);
      glds16((const char*)(A + (size_t)(m0 + row) * K + kt * BK) + kbs * 16,
             (char*)As + c * 1024);
    }
    #pragma unroll
    for (int i = 0; i < 2; ++i){                    // B: 16 chunks, 2/wave
      int c = wid * 2 + i;
      int row = c * 8 + srow;
      int kbs = skb ^ (row & 7);
      glds16((const char*)(BT + ((size_t)(blockIdx.x * ksteps + kt) * 128 + row) * 64) + kbs * 16,
             (char*)Bs + c * 1024);
    }
    __syncthreads();
    #pragma unroll
    for (int ks = 0; ks < 2; ++ks){
      bf16x8 af[4], bfr[4];
      #pragma unroll
      for (int m = 0; m < 4; ++m){
        int r = wm*64 + m*16 + l15;
        af[m] = *(const bf16x8*)((const char*)As + r*128 + (((ks*4 + l4) ^ (r & 7)) * 16));
      }
      #pragma unroll
      for (int n = 0; n < 4; ++n){
        int r = wn*64 + n*16 + l15;
        bfr[n] = *(const bf16x8*)((const char*)Bs + r*128 + (((ks*4 + l4) ^ (r & 7)) * 16));
      }
      #pragma unroll
      for (int m = 0; m < 4; ++m)
        #pragma unroll
        for (int n = 0; n < 4; ++n)
          acc[m][n] = __builtin_amdgcn_mfma_f32_16x16x32_bf16(af[m], bfr[n], acc[m][n], 0, 0, 0);
    }
    __syncthreads();
  }

  // ---- epilogue: direct sum of exp over this 128-col tile ----
  float bv[4]; bool val[4];
  #pragma unroll
  for (int n = 0; n < 4; ++n){
    int col = n0 + wn*64 + n*16 + l15;
    val[n] = col < N;
    bv[n] = val[n] ? bias[col] : 0.f;
  }
  #pragma unroll
  for (int m = 0; m < 4; ++m)
    #pragma unroll
    for (int q = 0; q < 4; ++q){
      int lrow = wm*64 + m*16 + l4*4 + q;
      int tr = trel_s[lrow];
      float Sl = 0.f;
      #pragma unroll
      for (int n = 0; n < 4; ++n){
        if (val[n]){
          float lg = acc[m][n][q] + bv[n];
          Sl += __expf(lg);
          int col = n0 + wn*64 + n*16 + l15;
          if (tr == col) tl[rowmap ? rowmap[m0 + lrow] : (m0 + lrow)] = lg;
        }
      }
      #pragma unroll
      for (int d = 1; d < 16; d <<= 1) Sl += __shfl_xor(Sl, d);
      if (l15 == 0) reds[wn][lrow] = Sl;
    }
  __syncthreads();
  if (wn == 0 && l15 == 0){
    #pragma unroll
    for (int m = 0; m < 4; ++m)
      #pragma unroll
      for (int q = 0; q < 4; ++q){
        int lrow = wm*64 + m*16 + l4*4 + q;
        P[(size_t)(m0 + lrow) * ntiles + blockIdx.x] = reds[0][lrow] + reds[1][lrow];
      }
  }
}

// ---------------- B-streaming GEMM for 1-K-step tails (t2 BK=64, t3 BK=32) --
template<int NC, int BK>
__global__ __launch_bounds__(256)
void k_gemm_lse_s(const u16* __restrict__ A, const u16* __restrict__ BT,
                  const float* __restrict__ bias, int N,
                  float* __restrict__ P, int ntiles,
                  const int* __restrict__ cntp, int bucket,
                  const int* __restrict__ tgt_rel, const int* __restrict__ rowmap,
                  float* __restrict__ tl)
{
  constexpr int CH  = BK / 8;          // 16B chunks per row
  constexpr int LPR = CH;
  constexpr int RPC = 64 / LPR;
  constexpr int CPW = (128 * BK * 2 / 1024) / 4;  // 1KB chunks per wave
  const int m0 = blockIdx.y * 128;
  if (m0 >= cntp[bucket]) return;
  const int cg = blockIdx.x;

  __shared__ u16 As[128 * BK];
  __shared__ u16 Bs[2][128 * BK];
  __shared__ float reds[2][128];
  __shared__ int trel_s[128];

  const int tid  = threadIdx.x;
  const int lane = tid & 63, wid = tid >> 6;
  const int wm = wid & 1, wn = wid >> 1;
  const int l15 = lane & 15, l4 = lane >> 4;
  const int srow = lane / LPR, skb = lane % LPR;

  if (tid < 128) trel_s[tid] = tgt_rel[m0 + tid];

  #pragma unroll
  for (int i = 0; i < CPW; ++i){
    int c = wid * CPW + i;
    int row = c * RPC + srow;
    int kbs = skb ^ (row & (CH - 1));
    glds16((const char*)(A + (size_t)(m0 + row) * BK) + kbs * 16,
           (char*)As + c * 1024);
  }
  {
    int ci0 = cg * NC;
    if (ci0 < ntiles){
      #pragma unroll
      for (int i = 0; i < CPW; ++i){
        int c = wid * CPW + i;
        int row = c * RPC + srow;
        int kbs = skb ^ (row & (CH - 1));
        glds16((const char*)(BT + (size_t)(ci0*128 + row) * BK) + kbs * 16,
               (char*)Bs[0] + c * 1024);
      }
    }
  }
  __syncthreads();

  int buf = 0;
  for (int ct = 0; ct < NC; ++ct){
    int ci = cg * NC + ct;
    if (ci >= ntiles) break;
    if (ct + 1 < NC && ci + 1 < ntiles){
      #pragma unroll
      for (int i = 0; i < CPW; ++i){
        int c = wid * CPW + i;
        int row = c * RPC + srow;
        int kbs = skb ^ (row & (CH - 1));
        glds16((const char*)(BT + (size_t)((ci+1)*128 + row) * BK) + kbs * 16,
               (char*)Bs[buf ^ 1] + c * 1024);
      }
    }
    f32x4 acc[4][4];
    #pragma unroll
    for (int m = 0; m < 4; ++m)
      #pragma unroll
      for (int n = 0; n < 4; ++n){ acc[m][n].x=0.f; acc[m][n].y=0.f; acc[m][n].z=0.f; acc[m][n].w=0.f; }
    #pragma unroll
    for (int ks = 0; ks < BK / 32; ++ks){
      bf16x8 af[4], bfr[4];
      #pragma unroll
      for (int m = 0; m < 4; ++m){
        int r = wm*64 + m*16 + l15;
        af[m] = *(const bf16x8*)((const char*)As + r*(BK*2) + (((ks*4 + l4) ^ (r & (CH-1))) * 16));
      }
      #pragma unroll
      for (int n = 0; n < 4; ++n){
        int r = wn*64 + n*16 + l15;
        bfr[n] = *(const bf16x8*)((const char*)Bs[buf] + r*(BK*2) + (((ks*4 + l4) ^ (r & (CH-1))) * 16));
      }
      #pragma unroll
      for (int m = 0; m < 4; ++m)
        #pragma unroll
        for (int n = 0; n < 4; ++n)
          acc[m][n] = __builtin_amdgcn_mfma_f32_16x16x32_bf16(af[m], bfr[n], acc[m][n], 0, 0, 0);
    }
    const int n0 = ci * 128;
    float bv[4]; bool val[4];
    #pragma unroll
    for (int n = 0; n < 4; ++n){
      int col = n0 + wn*64 + n*16 + l15;
      val[n] = col < N;
      bv[n] = val[n] ? bias[col] : 0.f;
    }
    #pragma unroll
    for (int m = 0; m < 4; ++m)
      #pragma unroll
      for (int q = 0; q < 4; ++q){
        int lrow = wm*64 + m*16 + l4*4 + q;
        int tr = trel_s[lrow];
        float Sl = 0.f;
        #pragma unroll
        for (int n = 0; n < 4; ++n){
          if (val[n]){
            float lg = acc[m][n][q] + bv[n];
            Sl += __expf(lg);
            int col = n0 + wn*64 + n*16 + l15;
            if (tr == col) tl[rowmap[m0 + lrow]] = lg;
          }
        }
        #pragma unroll
        for (int d = 1; d < 16; d <<= 1) Sl += __shfl_xor(Sl, d);
        if (l15 == 0) reds[wn][lrow] = Sl;
      }
    __syncthreads();
    if (wn == 0 && l15 == 0){
      #pragma unroll
      for (int m = 0; m < 4; ++m)
        #pragma unroll
        for (int q = 0; q < 4; ++q){
          int lrow = wm*64 + m*16 + l4*4 + q;
          P[(size_t)(m0 + lrow) * ntiles + ci] = reds[0][lrow] + reds[1][lrow];
        }
    }
    __syncthreads();
    buf ^= 1;
  }
}

// ---------------- final combine (P = f32 partial sums of exp) ----------------
__global__ void k_finalize(const int* __restrict__ tgt, const float* __restrict__ P,
                           const float* __restrict__ cl, const float* __restrict__ tl,
                           const int* __restrict__ pos, float* __restrict__ out)
{
  const int NT0 = 157, NT1 = 313, NT2 = 938, NT3 = 686;
  int n = blockIdx.x * 4 + (threadIdx.x >> 6);
  int lane = threadIdx.x & 63;
  int t = tgt[n];

  float s = 0.f;
  const float* p0 = P + (size_t)n * NT0;
  for (int i = lane; i < NT0; i += 64) s += p0[i];
  if (lane < 3) s += __expf(cl[n*3 + lane]);
  #pragma unroll
  for (int d = 1; d < 64; d <<= 1) s += __shfl_xor(s, d);
  float lse_head = logf(s);

  float nll;
  if (t < 20000){
    nll = lse_head - tl[n];
  } else {
    int seg, nt; size_t base;
    if      (t <  60000){ seg = 1; nt = NT1; base = (size_t)1024 * NT0; }
    else if (t < 180000){ seg = 2; nt = NT2; base = (size_t)1024 * (NT0 + NT1); }
    else                { seg = 3; nt = NT3; base = (size_t)1024 * (NT0 + NT1 + NT2); }
    float s2 = 0.f;
    const float* ps = P + base + (size_t)pos[n] * nt;
    for (int i = lane; i < nt; i += 64) s2 += ps[i];
    #pragma unroll
    for (int d = 1; d < 64; d <<= 1) s2 += __shfl_xor(s2, d);
    float lse_t = logf(s2);
    // reference quirk: bucket i uses head_lp[:, -i] == cluster logit index 3-i
    nll = lse_head - cl[n*3 + (3 - seg)] + lse_t - tl[n];
  }
  if (lane == 0) out[n] = nll;
}

// ---------------------------------------------------------------------------
extern "C" void kernel_launch(void* const* d_in, const int* in_sizes, int n_in,
                              void* d_out, int out_size, void* d_ws, size_t ws_size,
                              hipStream_t stream)
{
  const float* hidden = (const float*)d_in[0];
  const int*   target = (const int*)d_in[1];
  const float* W_head = (const float*)d_in[2];
  const float* b_head = (const float*)d_in[3];
  const float* W_clu  = (const float*)d_in[4];
  const float* b_clu  = (const float*)d_in[5];
  const float* W_p1   = (const float*)d_in[6];
  const float* W_t1   = (const float*)d_in[7];
  const float* b_t1   = (const float*)d_in[8];
  const float* W_p2   = (const float*)d_in[9];
  const float* W_t2   = (const float*)d_in[10];
  const float* b_t2   = (const float*)d_in[11];
  const float* W_p3   = (const float*)d_in[12];
  const float* W_t3   = (const float*)d_in[13];
  const float* b_t3   = (const float*)d_in[14];
  float* out = (float*)d_out;

  // workspace layout (bytes; big path needs ~100 MB)
  char* ws = (char*)d_ws;
  u16*   A0  = (u16*)(ws + 0);          // [1024][1024] bf16
  u16*   A1  = (u16*)(ws + 2097152);    // [1024][256]
  u16*   A2  = (u16*)(ws + 2621440);    // [1024][64]
  u16*   A3  = (u16*)(ws + 2752512);    // [1024][32]
  float* cl  = (float*)(ws + 2883584);  // [1024][3]
  float* tl  = (float*)(ws + 2895872);  // [1024]
  float* P   = (float*)(ws + 2899968);  // [1024][157+313+938+686] f32 (8.6MB)
  u16*   BTp = (u16*)(ws + 2899968);    // proj weights [400][1024]; dead
                                        // before head GEMM writes P
  u16*   BTh = (u16*)(ws + 11476992);   // head BT blocked [157][16][128][64]
  int*   cnt  = (int*)(ws + 52633600);  // [4]
  int*   idx1 = (int*)(ws + 52633856);
  int*   idx2 = (int*)(ws + 52637952);
  int*   idx3 = (int*)(ws + 52642048);
  int*   pos  = (int*)(ws + 52646144);
  u16*   A1c  = (u16*)(ws + 52650240);  // [1024][256]
  u16*   A2c  = (u16*)(ws + 53174528);  // [1024][64]
  u16*   A3c  = (u16*)(ws + 53305600);  // [1024][32]
  int*   tr0  = (int*)(ws + 53436672);  // [1024] x4, contiguous
  int*   tr1  = (int*)(ws + 53440768);
  int*   tr2  = (int*)(ws + 53444864);
  int*   tr3  = (int*)(ws + 53448960);
  u16*   BT1  = (u16*)(ws + 53453056);  // t1 blocked [313][4][128][64] (20.5MB)
  u16*   BT2  = (u16*)(ws + 73965824);  // [120064][64]  (15.4 MB)
  u16*   BT3  = (u16*)(ws + 89334016);  // [87808][32]   ( 5.6 MB)
  const size_t needA = 95000000;
  const bool bigws = ws_size >= needA;

  float* P0  = P;
  float* Pp1 = P + (size_t)1024 * 157;
  float* Pp2 = P + (size_t)1024 * (157 + 313);
  float* Pp3 = P + (size_t)1024 * (157 + 313 + 938);

  k_cvt_hidden<<<512, 256, 0, stream>>>(hidden, A0, cnt, tr0);
  k_compact<<<4, 256, 0, stream>>>(target, cnt, idx1, idx2, idx3, pos,
                                   tr0, tr1, tr2, tr3);

  // ---- transposes (R10 version) ----
  TJobs tj{}; int nb = 0;
  auto add = [&](const float* W, u16* B, int K, int N, int Kpad, int nrows, int blk){
    int nx = (nrows + 63) / 64;
    int ny = (Kpad + 63) / 64;
    tj.j[tj.nj++] = TJob{W, B, K, N, Kpad, nrows, nx, nb, blk};
    nb += nx * ny;
  };
  add(W_p1, BTp, 1024, 256, 1024, 256, 0);
  add(W_p2, BTp + (size_t)256*1024, 1024, 64, 1024, 64, 0);
  add(W_p3, BTp + (size_t)320*1024, 1024, 16, 1024, 16, 0);
  add(W_clu, BTp + (size_t)336*1024, 1024, 3, 1024, 64, 0);
  add(W_head, BTh, 1024, 20000, 1024, 20096, 1);
  if (bigws){
    add(W_t1, BT1, 256, 40000, 256, 40064, 1);
    add(W_t2, BT2, 64, 120000, 64, 120064, 0);
    add(W_t3, BT3, 16, 87735, 32, 87808, 0);
  }
  k_transpose_multi<<<nb, 256, 0, stream>>>(tj);

  k_proj_gemm<<<dim3(3, 4), 512, 0, stream>>>(A0, BTp, b_clu, A1, A2, A3, cl);
  k_gather<<<192, 256, 0, stream>>>(cnt, idx1, idx2, idx3, A1, A2, A3, A1c, A2c, A3c);

  // ---- GEMM+LSE per segment (head/t1: BM=256; t2/t3: B-streaming) ----
  k_gemm_lse256<<<dim3(157, 4), 512, 0, stream>>>(A0, BTh, b_head, 1024, 20000,
      P0, 157, nullptr, 0, tr0, nullptr, tl);

  if (bigws){
    k_gemm_lse256<<<dim3(313, 4), 512, 0, stream>>>(A1c, BT1, b_t1, 256, 40000,
        Pp1, 313, cnt, 0, tr1, idx1, tl);
    k_gemm_lse_s<4, 64><<<dim3(235, 8), 256, 0, stream>>>(A2c, BT2, b_t2, 120000,
        Pp2, 938, cnt, 1, tr2, idx2, tl);
    k_gemm_lse_s<4, 32><<<dim3(172, 8), 256, 0, stream>>>(A3c, BT3, b_t3, 87735,
        Pp3, 686, cnt, 2, tr3, idx3, tl);
  } else {
    // small ws: tails sequentially reuse BTh region (each fits in 41 MB)
    TJobs s1{}; s1.nj = 1; s1.j[0] = TJob{W_t1, BTh, 256, 40000, 256, 40064, 626, 0, 1};
    k_transpose_multi<<<626*4, 256, 0, stream>>>(s1);
    k_gemm_lse256<<<dim3(313, 4), 512, 0, stream>>>(A1c, BTh, b_t1, 256, 40000,
        Pp1, 313, cnt, 0, tr1, idx1, tl);
    TJobs s2{}; s2.nj = 1; s2.j[0] = TJob{W_t2, BTh, 64, 120000, 64, 120064, 1876, 0, 0};
    k_transpose_multi<<<1876, 256, 0, stream>>>(s2);
    k_gemm_lse_s<4, 64><<<dim3(235, 8), 256, 0, stream>>>(A2c, BTh, b_t2, 120000,
        Pp2, 938, cnt, 1, tr2, idx2, tl);
    TJobs s3{}; s3.nj = 1; s3.j[0] = TJob{W_t3, BTh, 16, 87735, 32, 87808, 1372, 0, 0};
    k_transpose_multi<<<1372, 256, 0, stream>>>(s3);
    k_gemm_lse_s<4, 32><<<dim3(172, 8), 256, 0, stream>>>(A3c, BTh, b_t3, 87735,
        Pp3, 686, cnt, 2, tr3, idx3, tl);
  }

  k_finalize<<<256, 256, 0, stream>>>(target, P, cl, tl, pos, out);
}

// Round 14
// 265.424 us; speedup vs baseline: 1.0551x; 1.0334x over previous
//
#include <hip/hip_runtime.h>
#include <cstdint>
#include <cstddef>

// ---------------------------------------------------------------------------
// Adaptive log-softmax NLL. bf16 MFMA GEMMs fused with online logsumexp.
// R14: base = R13 (274.3us). Tail transposes (t1/t2/t3, ~40us HBM-bound) are
// merged INTO the head-GEMM launch (k_mega: blocks 0..627 = BM256 head GEMM,
// dispatched first; blocks 628+ = transpose body). Head GEMM is not BW-bound
// (R3 ord-488), so the transpose traffic hides under its barrier stalls.
// First transpose launch now carries only proj+head jobs.
// ---------------------------------------------------------------------------

typedef unsigned short u16;
typedef __attribute__((ext_vector_type(8))) __bf16 bf16x8;
typedef __attribute__((ext_vector_type(8))) u16 u16x8;
typedef __attribute__((ext_vector_type(4))) float f32x4;

#define AS1 __attribute__((address_space(1)))
#define AS3 __attribute__((address_space(3)))

__device__ __forceinline__ u16 f2bf(float f){
  union { float f; unsigned u; } v; v.f = f;
  unsigned r = v.u + 0x7fffu + ((v.u >> 16) & 1u);  // RNE
  return (u16)(r >> 16);
}
__device__ __forceinline__ float bf2f(u16 x){
  union { unsigned u; float f; } v; v.u = ((unsigned)x) << 16;
  return v.f;
}
__device__ __forceinline__ void glds16(const void* g, void* l){
  __builtin_amdgcn_global_load_lds((AS1 unsigned*)(uintptr_t)g,
                                   (AS3 unsigned*)(unsigned)(uintptr_t)l, 16, 0, 0);
}

// ---------------- hidden f32 -> bf16 (+ init cnt and tgt_rel) ----------------
__global__ void k_cvt_hidden(const float* __restrict__ h, u16* __restrict__ a0,
                             int* __restrict__ cnt, int* __restrict__ trel){
  int g = blockIdx.x * 256 + threadIdx.x;
  if (g < 4096) trel[g] = -1;          // tr0..tr3, 1024 each, contiguous
  if (g < 4) cnt[g] = 0;
  int i = g * 8;
  f32x4 v0 = *(const f32x4*)(h + i);
  f32x4 v1 = *(const f32x4*)(h + i + 4);
  u16x8 o;
  o[0]=f2bf(v0.x); o[1]=f2bf(v0.y); o[2]=f2bf(v0.z); o[3]=f2bf(v0.w);
  o[4]=f2bf(v1.x); o[5]=f2bf(v1.y); o[6]=f2bf(v1.z); o[7]=f2bf(v1.w);
  *(u16x8*)(a0 + i) = o;
}

// ---------------- bucket compaction ----------------
// Order within a bucket is atomic-nondeterministic; harmless: per-row values
// are position-independent and results scatter back via pos[n]/idx[p].
__global__ void k_compact(const int* __restrict__ tgt, int* __restrict__ cnt,
                          int* __restrict__ idx1, int* __restrict__ idx2,
                          int* __restrict__ idx3, int* __restrict__ pos,
                          int* __restrict__ tr0, int* __restrict__ tr1,
                          int* __restrict__ tr2, int* __restrict__ tr3){
  int n = blockIdx.x * 256 + threadIdx.x;
  int t = tgt[n];
  int p = 0;
  tr0[n] = (t < 20000) ? t : -1;
  if (t >= 20000){
    int b = (t < 60000) ? 0 : (t < 180000 ? 1 : 2);
    p = atomicAdd(&cnt[b], 1);
    if (b == 0){ idx1[p] = n; tr1[p] = t - 20000; }
    else if (b == 1){ idx2[p] = n; tr2[p] = t - 60000; }
    else { idx3[p] = n; tr3[p] = t - 180000; }
  }
  pos[n] = p;
}

// ---------------- gather compacted tail-A rows ----------------
__global__ void k_gather(const int* __restrict__ cnt,
                         const int* __restrict__ idx1, const int* __restrict__ idx2,
                         const int* __restrict__ idx3,
                         const u16* __restrict__ A1, const u16* __restrict__ A2,
                         const u16* __restrict__ A3,
                         u16* __restrict__ A1c, u16* __restrict__ A2c,
                         u16* __restrict__ A3c){
  int u = blockIdx.x * 256 + threadIdx.x;
  const u16* src; u16* dst;
  if (u < 32768){                       // A1: 1024 rows x 32 chunks(8 elem)
    int r = u >> 5, c = u & 31;
    if (r >= cnt[0]) return;
    src = A1 + (size_t)idx1[r] * 256 + c * 8;
    dst = A1c + (size_t)r * 256 + c * 8;
  } else if (u < 40960){                // A2: 1024 x 8
    int v = u - 32768; int r = v >> 3, c = v & 7;
    if (r >= cnt[1]) return;
    src = A2 + (size_t)idx2[r] * 64 + c * 8;
    dst = A2c + (size_t)r * 64 + c * 8;
  } else {                              // A3 (32-wide): 1024 x 4
    int v = u - 40960; int r = v >> 2, c = v & 3;
    if (r >= cnt[2]) return;
    src = A3 + (size_t)idx3[r] * 32 + c * 8;
    dst = A3c + (size_t)r * 32 + c * 8;
  }
  *(u16x8*)dst = *(const u16x8*)src;
}

// ---------------- transpose job descriptors ----------------
// blocked element offset(n,k) = ((n>>7)*(Kpad>>6) + (k>>6))*8192 + (n&127)*64
//                               + (k&63)  -> 64x64 tile = one 8KB span.
struct TJob { const float* W; u16* BT; int K, N, Kpad, nrows, nx, base, blk; };
struct TJobs { TJob j[8]; int nj; };

// R10-proven transpose tile body; TPB = threads participating (stride).
template<int TPB>
__device__ __forceinline__ void transpose_tile(const TJobs& jobs, int id,
                                               float (*t)[65], int tid){
  int ji = 0;
  #pragma unroll
  for (int i = 1; i < 8; ++i)
    if (i < jobs.nj && id >= jobs.j[i].base) ji = i;
  TJob jb = jobs.j[ji];
  int local = id - jb.base;
  int bx = local % jb.nx;
  int by = local / jb.nx;

  const int n0 = bx * 64;
  const int k0 = by * 64;
  const bool al = (jb.N & 3) == 0;
  for (int i = tid; i < 64*16; i += TPB){
    int r = i >> 4, c4 = (i & 15) * 4;
    int k = k0 + r, n = n0 + c4;
    f32x4 v; v.x=0.f; v.y=0.f; v.z=0.f; v.w=0.f;
    if (k < jb.K){
      if (al && n + 3 < jb.N) v = *(const f32x4*)(jb.W + (size_t)k * jb.N + n);
      else { for (int q = 0; q < 4; ++q) if (n + q < jb.N) v[q] = jb.W[(size_t)k * jb.N + n + q]; }
    }
    t[r][c4] = v.x; t[r][c4+1] = v.y; t[r][c4+2] = v.z; t[r][c4+3] = v.w;
  }
  __syncthreads();
  for (int i = tid; i < 64*8; i += TPB){
    int rn = i >> 3, c8 = (i & 7) * 8;
    int n = n0 + rn;
    if (k0 + c8 < jb.Kpad && n < jb.nrows){
      u16x8 o;
      #pragma unroll
      for (int q = 0; q < 8; ++q) o[q] = f2bf(t[c8 + q][rn]);
      size_t off;
      if (jb.blk)
        off = (((size_t)(n >> 7) * (jb.Kpad >> 6) + (k0 >> 6)) * 128 + (n & 127)) * 64 + c8;
      else
        off = (size_t)n * jb.Kpad + k0 + c8;
      *(u16x8*)(jb.BT + off) = o;
    }
  }
}

__global__ void k_transpose_multi(TJobs jobs){
  __shared__ float t[64][65];
  transpose_tile<256>(jobs, blockIdx.x, t, threadIdx.x);
}

// ---------------- projection GEMM: A0[1024][1024] x BTp[400][1024]^T -------
__global__ __launch_bounds__(512)
void k_proj_gemm(const u16* __restrict__ A, const u16* __restrict__ BT,
                 const float* __restrict__ bc,
                 u16* __restrict__ A1, u16* __restrict__ A2,
                 u16* __restrict__ A3, float* __restrict__ cl)
{
  constexpr int BK = 64, K = 1024;
  __shared__ u16 As[256 * BK];
  __shared__ u16 Bs[128 * BK];
  const int tid  = threadIdx.x;
  const int lane = tid & 63, wid = tid >> 6;
  const int wm = wid & 3, wn = wid >> 2;
  const int l15 = lane & 15, l4 = lane >> 4;
  const int m0 = blockIdx.y * 256;
  const int n0 = blockIdx.x * 128;

  f32x4 acc[4][4];
  #pragma unroll
  for (int m = 0; m < 4; ++m)
    #pragma unroll
    for (int n = 0; n < 4; ++n){ acc[m][n].x=0.f; acc[m][n].y=0.f; acc[m][n].z=0.f; acc[m][n].w=0.f; }

  for (int kt = 0; kt < K / BK; ++kt){
    #pragma unroll
    for (int i = 0; i < 4; ++i){
      int c = wid * 4 + i;
      int row = c * 8 + lane / 8, kb = lane % 8;
      glds16((const char*)(A + (size_t)(m0 + row) * K + kt * BK) + kb * 16,
             (char*)As + c * 1024);
    }
    #pragma unroll
    for (int i = 0; i < 2; ++i){
      int c = wid * 2 + i;
      int row = c * 8 + lane / 8, kb = lane % 8;
      glds16((const char*)(BT + (size_t)(n0 + row) * K + kt * BK) + kb * 16,
             (char*)Bs + c * 1024);
    }
    __syncthreads();
    #pragma unroll
    for (int ks = 0; ks < 2; ++ks){
      bf16x8 af[4], bfr[4];
      #pragma unroll
      for (int m = 0; m < 4; ++m)
        af[m] = *(const bf16x8*)((const char*)As + (wm*64 + m*16 + l15) * (BK*2) + ks*64 + l4*16);
      #pragma unroll
      for (int n = 0; n < 4; ++n)
        bfr[n] = *(const bf16x8*)((const char*)Bs + (wn*64 + n*16 + l15) * (BK*2) + ks*64 + l4*16);
      #pragma unroll
      for (int m = 0; m < 4; ++m)
        #pragma unroll
        for (int n = 0; n < 4; ++n)
          acc[m][n] = __builtin_amdgcn_mfma_f32_16x16x32_bf16(af[m], bfr[n], acc[m][n], 0, 0, 0);
    }
    __syncthreads();
  }
  #pragma unroll
  for (int m = 0; m < 4; ++m)
    #pragma unroll
    for (int n = 0; n < 4; ++n)
      #pragma unroll
      for (int q = 0; q < 4; ++q){
        int c = n0 + wn*64 + n*16 + l15;
        int r = m0 + wm*64 + m*16 + l4*4 + q;
        float v = acc[m][n][q];
        if (c < 256)      A1[(size_t)r*256 + c] = f2bf(v);
        else if (c < 320) A2[(size_t)r*64 + (c-256)] = f2bf(v);
        else if (c < 336){ u16* p = A3 + (size_t)r*32 + (c-320);
                           p[0] = f2bf(v); p[16] = 0; }
        else if (c < 339) cl[(size_t)r*3 + (c-336)] = v + bc[c-336];
      }
}

// ---------------- BM=256 GEMM body (R13-proven), shared-mem passed in ------
__device__ __forceinline__
void gemm256_body(const u16* __restrict__ A, const u16* __restrict__ BT,
                  const float* __restrict__ bias, int K, int N,
                  float* __restrict__ P, int ntiles, int cb, int rb,
                  const int* __restrict__ tgt_rel, const int* __restrict__ rowmap,
                  float* __restrict__ tl,
                  u16* As, u16* Bs, float* reds /*[2][256] flat*/, int* trel_s)
{
  constexpr int BK = 64;
  const int tid  = threadIdx.x;
  const int lane = tid & 63, wid = tid >> 6;
  const int wm = wid & 3, wn = wid >> 2;
  const int l15 = lane & 15, l4 = lane >> 4;
  const int m0 = rb * 256;
  const int n0 = cb * 128;
  const int srow = lane >> 3, skb = lane & 7;

  if (tid < 256) trel_s[tid] = tgt_rel[m0 + tid];

  f32x4 acc[4][4];
  #pragma unroll
  for (int m = 0; m < 4; ++m)
    #pragma unroll
    for (int n = 0; n < 4; ++n){ acc[m][n].x=0.f; acc[m][n].y=0.f; acc[m][n].z=0.f; acc[m][n].w=0.f; }

  const int ksteps = K / BK;
  for (int kt = 0; kt < ksteps; ++kt){
    #pragma unroll
    for (int i = 0; i < 4; ++i){                    // A: 32 chunks, 4/wave
      int c = wid * 4 + i;
      int row = c * 8 + srow;
      int kbs = skb ^ (row & 7);
      glds16((const char*)(A + (size_t)(m0 + row) * K + kt * BK) + kbs * 16,
             (char*)As + c * 1024);
    }
    #pragma unroll
    for (int i = 0; i < 2; ++i){                    // B: 16 chunks, 2/wave
      int c = wid * 2 + i;
      int row = c * 8 + srow;
      int kbs = skb ^ (row & 7);
      glds16((const char*)(BT + ((size_t)(cb * ksteps + kt) * 128 + row) * 64) + kbs * 16,
             (char*)Bs + c * 1024);
    }
    __syncthreads();
    #pragma unroll
    for (int ks = 0; ks < 2; ++ks){
      bf16x8 af[4], bfr[4];
      #pragma unroll
      for (int m = 0; m < 4; ++m){
        int r = wm*64 + m*16 + l15;
        af[m] = *(const bf16x8*)((const char*)As + r*128 + (((ks*4 + l4) ^ (r & 7)) * 16));
      }
      #pragma unroll
      for (int n = 0; n < 4; ++n){
        int r = wn*64 + n*16 + l15;
        bfr[n] = *(const bf16x8*)((const char*)Bs + r*128 + (((ks*4 + l4) ^ (r & 7)) * 16));
      }
      #pragma unroll
      for (int m = 0; m < 4; ++m)
        #pragma unroll
        for (int n = 0; n < 4; ++n)
          acc[m][n] = __builtin_amdgcn_mfma_f32_16x16x32_bf16(af[m], bfr[n], acc[m][n], 0, 0, 0);
    }
    __syncthreads();
  }

  // ---- epilogue: direct sum of exp over this 128-col tile ----
  float bv[4]; bool val[4];
  #pragma unroll
  for (int n = 0; n < 4; ++n){
    int col = n0 + wn*64 + n*16 + l15;
    val[n] = col < N;
    bv[n] = val[n] ? bias[col] : 0.f;
  }
  #pragma unroll
  for (int m = 0; m < 4; ++m)
    #pragma unroll
    for (int q = 0; q < 4; ++q){
      int lrow = wm*64 + m*16 + l4*4 + q;
      int tr = trel_s[lrow];
      float Sl = 0.f;
      #pragma unroll
      for (int n = 0; n < 4; ++n){
        if (val[n]){
          float lg = acc[m][n][q] + bv[n];
          Sl += __expf(lg);
          int col = n0 + wn*64 + n*16 + l15;
          if (tr == col) tl[rowmap ? rowmap[m0 + lrow] : (m0 + lrow)] = lg;
        }
      }
      #pragma unroll
      for (int d = 1; d < 16; d <<= 1) Sl += __shfl_xor(Sl, d);
      if (l15 == 0) reds[wn*256 + lrow] = Sl;
    }
  __syncthreads();
  if (wn == 0 && l15 == 0){
    #pragma unroll
    for (int m = 0; m < 4; ++m)
      #pragma unroll
      for (int q = 0; q < 4; ++q){
        int lrow = wm*64 + m*16 + l4*4 + q;
        P[(size_t)(m0 + lrow) * ntiles + cb] = reds[lrow] + reds[256 + lrow];
      }
  }
}

// ---------------- standalone BM=256 GEMM (t1, small-ws head) --------------
__global__ __launch_bounds__(512)
void k_gemm_lse256(const u16* __restrict__ A, const u16* __restrict__ BT,
                   const float* __restrict__ bias, int K, int N,
                   float* __restrict__ P, int ntiles,
                   const int* __restrict__ cntp, int bucket,
                   const int* __restrict__ tgt_rel, const int* __restrict__ rowmap,
                   float* __restrict__ tl)
{
  if (cntp && (int)(blockIdx.y * 256) >= cntp[bucket]) return;
  __shared__ u16 As[256 * 64];
  __shared__ u16 Bs[128 * 64];
  __shared__ float reds[2 * 256];
  __shared__ int trel_s[256];
  gemm256_body(A, BT, bias, K, N, P, ntiles, blockIdx.x, blockIdx.y,
               tgt_rel, rowmap, tl, As, Bs, reds, trel_s);
}

// ---------------- mega: head GEMM (blocks < gb) + tail transposes ----------
__global__ __launch_bounds__(512)
void k_mega(const u16* __restrict__ A, const u16* __restrict__ BT,
            const float* __restrict__ bias, int ntiles,
            float* __restrict__ P, const int* __restrict__ tgt_rel,
            float* __restrict__ tl, int gb, TJobs tails)
{
  __shared__ __align__(16) char smem[52224];   // GEMM: As32K|Bs16K|reds2K|trel1K
  if ((int)blockIdx.x < gb){
    u16* As = (u16*)smem;
    u16* Bs = (u16*)(smem + 32768);
    float* reds = (float*)(smem + 49152);
    int* trel_s = (int*)(smem + 51200);
    gemm256_body(A, BT, bias, 1024, 20000, P, ntiles,
                 blockIdx.x % ntiles, blockIdx.x / ntiles,
                 tgt_rel, nullptr, tl, As, Bs, reds, trel_s);
  } else {
    float (*t)[65] = (float(*)[65])smem;       // 16.6KB of the union
    transpose_tile<512>(tails, blockIdx.x - gb, t, threadIdx.x);
  }
}

// ---------------- B-streaming GEMM for 1-K-step tails (t2 BK=64, t3 BK=32) --
template<int NC, int BK>
__global__ __launch_bounds__(256)
void k_gemm_lse_s(const u16* __restrict__ A, const u16* __restrict__ BT,
                  const float* __restrict__ bias, int N,
                  float* __restrict__ P, int ntiles,
                  const int* __restrict__ cntp, int bucket,
                  const int* __restrict__ tgt_rel, const int* __restrict__ rowmap,
                  float* __restrict__ tl)
{
  constexpr int CH  = BK / 8;          // 16B chunks per row
  constexpr int LPR = CH;
  constexpr int RPC = 64 / LPR;
  constexpr int CPW = (128 * BK * 2 / 1024) / 4;  // 1KB chunks per wave
  const int m0 = blockIdx.y * 128;
  if (m0 >= cntp[bucket]) return;
  const int cg = blockIdx.x;

  __shared__ u16 As[128 * BK];
  __shared__ u16 Bs[2][128 * BK];
  __shared__ float reds[2][128];
  __shared__ int trel_s[128];

  const int tid  = threadIdx.x;
  const int lane = tid & 63, wid = tid >> 6;
  const int wm = wid & 1, wn = wid >> 1;
  const int l15 = lane & 15, l4 = lane >> 4;
  const int srow = lane / LPR, skb = lane % LPR;

  if (tid < 128) trel_s[tid] = tgt_rel[m0 + tid];

  #pragma unroll
  for (int i = 0; i < CPW; ++i){
    int c = wid * CPW + i;
    int row = c * RPC + srow;
    int kbs = skb ^ (row & (CH - 1));
    glds16((const char*)(A + (size_t)(m0 + row) * BK) + kbs * 16,
           (char*)As + c * 1024);
  }
  {
    int ci0 = cg * NC;
    if (ci0 < ntiles){
      #pragma unroll
      for (int i = 0; i < CPW; ++i){
        int c = wid * CPW + i;
        int row = c * RPC + srow;
        int kbs = skb ^ (row & (CH - 1));
        glds16((const char*)(BT + (size_t)(ci0*128 + row) * BK) + kbs * 16,
               (char*)Bs[0] + c * 1024);
      }
    }
  }
  __syncthreads();

  int buf = 0;
  for (int ct = 0; ct < NC; ++ct){
    int ci = cg * NC + ct;
    if (ci >= ntiles) break;
    if (ct + 1 < NC && ci + 1 < ntiles){
      #pragma unroll
      for (int i = 0; i < CPW; ++i){
        int c = wid * CPW + i;
        int row = c * RPC + srow;
        int kbs = skb ^ (row & (CH - 1));
        glds16((const char*)(BT + (size_t)((ci+1)*128 + row) * BK) + kbs * 16,
               (char*)Bs[buf ^ 1] + c * 1024);
      }
    }
    f32x4 acc[4][4];
    #pragma unroll
    for (int m = 0; m < 4; ++m)
      #pragma unroll
      for (int n = 0; n < 4; ++n){ acc[m][n].x=0.f; acc[m][n].y=0.f; acc[m][n].z=0.f; acc[m][n].w=0.f; }
    #pragma unroll
    for (int ks = 0; ks < BK / 32; ++ks){
      bf16x8 af[4], bfr[4];
      #pragma unroll
      for (int m = 0; m < 4; ++m){
        int r = wm*64 + m*16 + l15;
        af[m] = *(const bf16x8*)((const char*)As + r*(BK*2) + (((ks*4 + l4) ^ (r & (CH-1))) * 16));
      }
      #pragma unroll
      for (int n = 0; n < 4; ++n){
        int r = wn*64 + n*16 + l15;
        bfr[n] = *(const bf16x8*)((const char*)Bs[buf] + r*(BK*2) + (((ks*4 + l4) ^ (r & (CH-1))) * 16));
      }
      #pragma unroll
      for (int m = 0; m < 4; ++m)
        #pragma unroll
        for (int n = 0; n < 4; ++n)
          acc[m][n] = __builtin_amdgcn_mfma_f32_16x16x32_bf16(af[m], bfr[n], acc[m][n], 0, 0, 0);
    }
    const int n0 = ci * 128;
    float bv[4]; bool val[4];
    #pragma unroll
    for (int n = 0; n < 4; ++n){
      int col = n0 + wn*64 + n*16 + l15;
      val[n] = col < N;
      bv[n] = val[n] ? bias[col] : 0.f;
    }
    #pragma unroll
    for (int m = 0; m < 4; ++m)
      #pragma unroll
      for (int q = 0; q < 4; ++q){
        int lrow = wm*64 + m*16 + l4*4 + q;
        int tr = trel_s[lrow];
        float Sl = 0.f;
        #pragma unroll
        for (int n = 0; n < 4; ++n){
          if (val[n]){
            float lg = acc[m][n][q] + bv[n];
            Sl += __expf(lg);
            int col = n0 + wn*64 + n*16 + l15;
            if (tr == col) tl[rowmap[m0 + lrow]] = lg;
          }
        }
        #pragma unroll
        for (int d = 1; d < 16; d <<= 1) Sl += __shfl_xor(Sl, d);
        if (l15 == 0) reds[wn][lrow] = Sl;
      }
    __syncthreads();
    if (wn == 0 && l15 == 0){
      #pragma unroll
      for (int m = 0; m < 4; ++m)
        #pragma unroll
        for (int q = 0; q < 4; ++q){
          int lrow = wm*64 + m*16 + l4*4 + q;
          P[(size_t)(m0 + lrow) * ntiles + ci] = reds[0][lrow] + reds[1][lrow];
        }
    }
    __syncthreads();
    buf ^= 1;
  }
}

// ---------------- final combine (P = f32 partial sums of exp) ----------------
__global__ void k_finalize(const int* __restrict__ tgt, const float* __restrict__ P,
                           const float* __restrict__ cl, const float* __restrict__ tl,
                           const int* __restrict__ pos, float* __restrict__ out)
{
  const int NT0 = 157, NT1 = 313, NT2 = 938, NT3 = 686;
  int n = blockIdx.x * 4 + (threadIdx.x >> 6);
  int lane = threadIdx.x & 63;
  int t = tgt[n];

  float s = 0.f;
  const float* p0 = P + (size_t)n * NT0;
  for (int i = lane; i < NT0; i += 64) s += p0[i];
  if (lane < 3) s += __expf(cl[n*3 + lane]);
  #pragma unroll
  for (int d = 1; d < 64; d <<= 1) s += __shfl_xor(s, d);
  float lse_head = logf(s);

  float nll;
  if (t < 20000){
    nll = lse_head - tl[n];
  } else {
    int seg, nt; size_t base;
    if      (t <  60000){ seg = 1; nt = NT1; base = (size_t)1024 * NT0; }
    else if (t < 180000){ seg = 2; nt = NT2; base = (size_t)1024 * (NT0 + NT1); }
    else                { seg = 3; nt = NT3; base = (size_t)1024 * (NT0 + NT1 + NT2); }
    float s2 = 0.f;
    const float* ps = P + base + (size_t)pos[n] * nt;
    for (int i = lane; i < nt; i += 64) s2 += ps[i];
    #pragma unroll
    for (int d = 1; d < 64; d <<= 1) s2 += __shfl_xor(s2, d);
    float lse_t = logf(s2);
    // reference quirk: bucket i uses head_lp[:, -i] == cluster logit index 3-i
    nll = lse_head - cl[n*3 + (3 - seg)] + lse_t - tl[n];
  }
  if (lane == 0) out[n] = nll;
}

// ---------------------------------------------------------------------------
extern "C" void kernel_launch(void* const* d_in, const int* in_sizes, int n_in,
                              void* d_out, int out_size, void* d_ws, size_t ws_size,
                              hipStream_t stream)
{
  const float* hidden = (const float*)d_in[0];
  const int*   target = (const int*)d_in[1];
  const float* W_head = (const float*)d_in[2];
  const float* b_head = (const float*)d_in[3];
  const float* W_clu  = (const float*)d_in[4];
  const float* b_clu  = (const float*)d_in[5];
  const float* W_p1   = (const float*)d_in[6];
  const float* W_t1   = (const float*)d_in[7];
  const float* b_t1   = (const float*)d_in[8];
  const float* W_p2   = (const float*)d_in[9];
  const float* W_t2   = (const float*)d_in[10];
  const float* b_t2   = (const float*)d_in[11];
  const float* W_p3   = (const float*)d_in[12];
  const float* W_t3   = (const float*)d_in[13];
  const float* b_t3   = (const float*)d_in[14];
  float* out = (float*)d_out;

  // workspace layout (bytes; big path needs ~100 MB)
  char* ws = (char*)d_ws;
  u16*   A0  = (u16*)(ws + 0);          // [1024][1024] bf16
  u16*   A1  = (u16*)(ws + 2097152);    // [1024][256]
  u16*   A2  = (u16*)(ws + 2621440);    // [1024][64]
  u16*   A3  = (u16*)(ws + 2752512);    // [1024][32]
  float* cl  = (float*)(ws + 2883584);  // [1024][3]
  float* tl  = (float*)(ws + 2895872);  // [1024]
  float* P   = (float*)(ws + 2899968);  // [1024][157+313+938+686] f32 (8.6MB)
  u16*   BTp = (u16*)(ws + 2899968);    // proj weights [400][1024]; dead
                                        // before head GEMM writes P
  u16*   BTh = (u16*)(ws + 11476992);   // head BT blocked [157][16][128][64]
  int*   cnt  = (int*)(ws + 52633600);  // [4]
  int*   idx1 = (int*)(ws + 52633856);
  int*   idx2 = (int*)(ws + 52637952);
  int*   idx3 = (int*)(ws + 52642048);
  int*   pos  = (int*)(ws + 52646144);
  u16*   A1c  = (u16*)(ws + 52650240);  // [1024][256]
  u16*   A2c  = (u16*)(ws + 53174528);  // [1024][64]
  u16*   A3c  = (u16*)(ws + 53305600);  // [1024][32]
  int*   tr0  = (int*)(ws + 53436672);  // [1024] x4, contiguous
  int*   tr1  = (int*)(ws + 53440768);
  int*   tr2  = (int*)(ws + 53444864);
  int*   tr3  = (int*)(ws + 53448960);
  u16*   BT1  = (u16*)(ws + 53453056);  // t1 blocked [313][4][128][64] (20.5MB)
  u16*   BT2  = (u16*)(ws + 73965824);  // [120064][64]  (15.4 MB)
  u16*   BT3  = (u16*)(ws + 89334016);  // [87808][32]   ( 5.6 MB)
  const size_t needA = 95000000;
  const bool bigws = ws_size >= needA;

  float* P0  = P;
  float* Pp1 = P + (size_t)1024 * 157;
  float* Pp2 = P + (size_t)1024 * (157 + 313);
  float* Pp3 = P + (size_t)1024 * (157 + 313 + 938);

  k_cvt_hidden<<<512, 256, 0, stream>>>(hidden, A0, cnt, tr0);
  k_compact<<<4, 256, 0, stream>>>(target, cnt, idx1, idx2, idx3, pos,
                                   tr0, tr1, tr2, tr3);

  auto addj = [](TJobs& tj, int& nb, const float* W, u16* B, int K, int N,
                 int Kpad, int nrows, int blk){
    int nx = (nrows + 63) / 64;
    int ny = (Kpad + 63) / 64;
    tj.j[tj.nj++] = TJob{W, B, K, N, Kpad, nrows, nx, nb, blk};
    nb += nx * ny;
  };

  if (bigws){
    // ---- stage 1 transposes: proj + head only ----
    TJobs tj{}; int nb = 0;
    addj(tj, nb, W_p1, BTp, 1024, 256, 1024, 256, 0);
    addj(tj, nb, W_p2, BTp + (size_t)256*1024, 1024, 64, 1024, 64, 0);
    addj(tj, nb, W_p3, BTp + (size_t)320*1024, 1024, 16, 1024, 16, 0);
    addj(tj, nb, W_clu, BTp + (size_t)336*1024, 1024, 3, 1024, 64, 0);
    addj(tj, nb, W_head, BTh, 1024, 20000, 1024, 20096, 1);
    k_transpose_multi<<<nb, 256, 0, stream>>>(tj);

    k_proj_gemm<<<dim3(3, 4), 512, 0, stream>>>(A0, BTp, b_clu, A1, A2, A3, cl);
    k_gather<<<192, 256, 0, stream>>>(cnt, idx1, idx2, idx3, A1, A2, A3, A1c, A2c, A3c);

    // ---- mega: head GEMM (628 blocks first) + tail transposes ----
    TJobs tt{}; int nbT = 0;
    addj(tt, nbT, W_t1, BT1, 256, 40000, 256, 40064, 1);
    addj(tt, nbT, W_t2, BT2, 64, 120000, 64, 120064, 0);
    addj(tt, nbT, W_t3, BT3, 16, 87735, 32, 87808, 0);
    const int gb = 157 * 4;
    k_mega<<<gb + nbT, 512, 0, stream>>>(A0, BTh, b_head, 157, P0, tr0, tl, gb, tt);

    k_gemm_lse256<<<dim3(313, 4), 512, 0, stream>>>(A1c, BT1, b_t1, 256, 40000,
        Pp1, 313, cnt, 0, tr1, idx1, tl);
    k_gemm_lse_s<4, 64><<<dim3(235, 8), 256, 0, stream>>>(A2c, BT2, b_t2, 120000,
        Pp2, 938, cnt, 1, tr2, idx2, tl);
    k_gemm_lse_s<4, 32><<<dim3(172, 8), 256, 0, stream>>>(A3c, BT3, b_t3, 87735,
        Pp3, 686, cnt, 2, tr3, idx3, tl);
  } else {
    // small ws: R13 sequential path, tails reuse BTh region
    TJobs tj{}; int nb = 0;
    addj(tj, nb, W_p1, BTp, 1024, 256, 1024, 256, 0);
    addj(tj, nb, W_p2, BTp + (size_t)256*1024, 1024, 64, 1024, 64, 0);
    addj(tj, nb, W_p3, BTp + (size_t)320*1024, 1024, 16, 1024, 16, 0);
    addj(tj, nb, W_clu, BTp + (size_t)336*1024, 1024, 3, 1024, 64, 0);
    addj(tj, nb, W_head, BTh, 1024, 20000, 1024, 20096, 1);
    k_transpose_multi<<<nb, 256, 0, stream>>>(tj);

    k_proj_gemm<<<dim3(3, 4), 512, 0, stream>>>(A0, BTp, b_clu, A1, A2, A3, cl);
    k_gather<<<192, 256, 0, stream>>>(cnt, idx1, idx2, idx3, A1, A2, A3, A1c, A2c, A3c);

    k_gemm_lse256<<<dim3(157, 4), 512, 0, stream>>>(A0, BTh, b_head, 1024, 20000,
        P0, 157, nullptr, 0, tr0, nullptr, tl);

    TJobs s1{}; int n1 = 0;
    addj(s1, n1, W_t1, BTh, 256, 40000, 256, 40064, 1);
    k_transpose_multi<<<n1, 256, 0, stream>>>(s1);
    k_gemm_lse256<<<dim3(313, 4), 512, 0, stream>>>(A1c, BTh, b_t1, 256, 40000,
        Pp1, 313, cnt, 0, tr1, idx1, tl);
    TJobs s2{}; int n2 = 0;
    addj(s2, n2, W_t2, BTh, 64, 120000, 64, 120064, 0);
    k_transpose_multi<<<n2, 256, 0, stream>>>(s2);
    k_gemm_lse_s<4, 64><<<dim3(235, 8), 256, 0, stream>>>(A2c, BTh, b_t2, 120000,
        Pp2, 938, cnt, 1, tr2, idx2, tl);
    TJobs s3{}; int n3 = 0;
    addj(s3, n3, W_t3, BTh, 16, 87735, 32, 87808, 0);
    k_transpose_multi<<<n3, 256, 0, stream>>>(s3);
    k_gemm_lse_s<4, 32><<<dim3(172, 8), 256, 0, stream>>>(A3c, BTh, b_t3, 87735,
        Pp3, 686, cnt, 2, tr3, idx3, tl);
  }

  k_finalize<<<256, 256, 0, stream>>>(target, P, cl, tl, pos, out);
}